// Round 12
// baseline (321.687 us; speedup 1.0000x reference)
//
#include <hip/hip_runtime.h>
#include <hip/hip_bf16.h>
#include <stdint.h>

// Problem constants (fixed by reference)
#define B_  4
#define N_  8192
#define M_  8192
#define D_  64
#define KP  96    // padded K: 64 data + (norm_hi, norm_lo, 1, 1) + 28 zeros
#define NT_ 64
#define MT_ 64
#define RBN ((B_ * N_) / 16)     // 2048 16-row blocks on A side
#define INF_BITS 0x7F800000      // +inf bits; signed-int min == float min for our range

typedef __attribute__((ext_vector_type(8))) short bhalf8;   // 8 bf16 (MFMA A/B frag)
typedef __attribute__((ext_vector_type(4))) float f32x4;    // MFMA C/D frag

// ---- workspace layout ----
// A'/B': bf16 fragment-chunk order (see prep). K=96 fuses norms so MFMA emits full distances.
// rowglob[32768] colglob[32768]: per-point mins (float bits, atomicMin). gates[512] after them.
// LESSONS: keep LDS tiny + VGPR <=80-ish (occupancy is the tile's limiter: R9/R10);
// never a centralized single-block finalize (R10: 40us idle-GPU tail);
// global atomicMin flush is fine (R7); per-launch overhead ~15us -> 2 dispatches.
static const size_t OFF_A   = 0;
static const size_t OFF_B   = (size_t)B_ * N_ * KP * 2;                   // 6,291,456
static const size_t OFF_RG  = OFF_B + (size_t)B_ * M_ * KP * 2;           // 12,582,912
static const size_t OFF_CG  = OFF_RG + (size_t)B_ * N_ * 4;               // +128 KB
static const size_t OFF_GT  = OFF_CG + (size_t)B_ * M_ * 4;               // +128 KB

__device__ __forceinline__ short bf16bits(float x) {
    union { __hip_bfloat16 h; unsigned short u; } cv;
    cv.h = __float2bfloat16(x);
    return (short)cv.u;
}
__device__ __forceinline__ float min3f(float a, float b, float c) {
    return fminf(fminf(a, b), c);   // -> v_min3_f32
}

// ---------------- prep: K=96 fused-norm fragment layout; init min buffers + gates + out ----------------
__global__ __launch_bounds__(256) void chamfer_prep(
        const float* __restrict__ f, const float* __restrict__ f2,
        unsigned short* __restrict__ Ap, unsigned short* __restrict__ Bp,
        int* __restrict__ minbuf, float* __restrict__ out) {
    const int tid = threadIdx.x;
    const int gid = blockIdx.x * 256 + tid;
    if (gid == 0) out[0] = 0.f;
    if (gid < 66048) minbuf[gid] = (gid < 65536) ? INF_BITS : 0;  // rowglob+colglob | gates

    const int w = gid >> 6;                          // 16-row block id, 0..4095
    const int lane = tid & 63;
    const int q = lane >> 4, c = lane & 15;
    const bool isA = w < RBN;
    const int rb = isA ? w : w - RBN;
    const float* src = isA ? f : f2;
    unsigned short* dst = isA ? Ap : Bp;
    const float scale = isA ? -2.0f : 1.0f;          // fold the -2 into A; exact in bf16

    const float* row = src + ((size_t)rb * 16 + c) * 64;
    f32x4 u0 = *(const f32x4*)(row + q * 8);
    f32x4 u1 = *(const f32x4*)(row + q * 8 + 4);
    f32x4 u2 = *(const f32x4*)(row + 32 + q * 8);
    f32x4 u3 = *(const f32x4*)(row + 32 + q * 8 + 4);

    float ss = 0.f;
    #pragma unroll
    for (int k = 0; k < 4; k++)
        ss += u0[k] * u0[k] + u1[k] * u1[k] + u2[k] * u2[k] + u3[k] * u3[k];
    ss += __shfl_xor(ss, 16, 64);
    ss += __shfl_xor(ss, 32, 64);                    // full ||row c||^2 in every lane

    bhalf8 o0, o1;
    #pragma unroll
    for (int k = 0; k < 4; k++) {
        o0[k]     = bf16bits(u0[k] * scale);
        o0[4 + k] = bf16bits(u1[k] * scale);
        o1[k]     = bf16bits(u2[k] * scale);
        o1[4 + k] = bf16bits(u3[k] * scale);
    }
    bhalf8 o2 = {0, 0, 0, 0, 0, 0, 0, 0};            // k=64..95 zeros except q==0 lanes
    if (q == 0) {
        float nh = __bfloat162float(__float2bfloat16(ss));  // hi part, exact in bf16
        float nl = ss - nh;                                  // residual
        const short one = 0x3F80;                            // bf16 1.0
        if (isA) { o2[0] = bf16bits(nh); o2[1] = bf16bits(nl); o2[2] = one; o2[3] = one; }
        else     { o2[0] = one; o2[1] = one; o2[2] = bf16bits(nh); o2[3] = bf16bits(nl); }
    }
    *(bhalf8*)(dst + ((size_t)(rb * 3 + 0) * 64 + lane) * 8) = o0;
    *(bhalf8*)(dst + ((size_t)(rb * 3 + 1) * 64 + lane) * 8) = o1;
    *(bhalf8*)(dst + ((size_t)(rb * 3 + 2) * 64 + lane) * 8) = o2;
}

// ---------------- tile kernel: R5-verbatim loop + distributed last-contributor finalize ----------------
__global__ __launch_bounds__(256, 2) void chamfer_tile(
        const unsigned short* __restrict__ Ap, const unsigned short* __restrict__ Bp,
        int* __restrict__ rowglob, int* __restrict__ colglob,
        int* __restrict__ gates, float* __restrict__ out) {
    const int mc = blockIdx.x;   // 0..7 : 8-tile mt chunk
    const int nt = blockIdx.y;   // 0..63
    const int b  = blockIdx.z;   // 0..3
    const int tid = threadIdx.x;
    const int wave = tid >> 6, lane = tid & 63;
    const int wr = wave >> 1, wc = wave & 1;
    const int q = lane >> 4, c = lane & 15;

    __shared__ int colmin[8][128];   // per-mt col mins, float bits, signed-int order (4 KB)
    __shared__ int rowmin[128];
    #pragma unroll
    for (int k = 0; k < 4; k++) ((int*)colmin)[k * 256 + tid] = INF_BITS;
    if (tid < 128) rowmin[tid] = INF_BITS;
    __syncthreads();

    // A fragments: rows nt*128 + wr*64 + i*16 + c, 3 k-steps. Loaded once.
    const int rbA0 = b * 512 + nt * 8 + wr * 4;
    bhalf8 af[4][3];
    #pragma unroll
    for (int i = 0; i < 4; i++)
        #pragma unroll
        for (int ks = 0; ks < 3; ks++)
            af[i][ks] = *(const bhalf8*)(Ap + ((size_t)((rbA0 + i) * 3 + ks) * 64 + lane) * 8);

    f32x4 rv[4];                 // running row-min, rows i*16+q*4+r (this wave's 64 rows)
    #pragma unroll
    for (int i = 0; i < 4; i++) rv[i] = (f32x4){3.0e38f, 3.0e38f, 3.0e38f, 3.0e38f};

    const f32x4 zero4 = {0.f, 0.f, 0.f, 0.f};

    auto loadB = [&](int s, bhalf8 (&bf)[2][3]) {
        const int rbB = b * 512 + (mc * 8 + (s >> 1)) * 8 + wc * 4 + (s & 1) * 2;
        #pragma unroll
        for (int jj = 0; jj < 2; jj++)
            #pragma unroll
            for (int ks = 0; ks < 3; ks++)
                bf[jj][ks] = *(const bhalf8*)(Bp + ((size_t)((rbB + jj) * 3 + ks) * 64 + lane) * 8);
    };

    auto process = [&](int s, bhalf8 (&bf)[2][3]) {
        f32x4 acc[4][2];
        #pragma unroll
        for (int i = 0; i < 4; i++)
            #pragma unroll
            for (int jj = 0; jj < 2; jj++)
                acc[i][jj] = __builtin_amdgcn_mfma_f32_16x16x32_bf16(af[i][0], bf[jj][0], zero4, 0, 0, 0);
        #pragma unroll
        for (int ks = 1; ks < 3; ks++)
            #pragma unroll
            for (int i = 0; i < 4; i++)
                #pragma unroll
                for (int jj = 0; jj < 2; jj++)
                    acc[i][jj] = __builtin_amdgcn_mfma_f32_16x16x32_bf16(af[i][ks], bf[jj][ks], acc[i][jj], 0, 0, 0);

        // row-min: 16 v_min3
        #pragma unroll
        for (int i = 0; i < 4; i++)
            #pragma unroll
            for (int r = 0; r < 4; r++)
                rv[i][r] = fminf(fminf(acc[i][0][r], acc[i][1][r]), rv[i][r]);

        // col-min over this lane's 16 rows -> fire-and-forget ds_min
        const int mtl = s >> 1;
        #pragma unroll
        for (int jj = 0; jj < 2; jj++) {
            float t0 = min3f(acc[0][jj][0], acc[0][jj][1], acc[0][jj][2]);
            float t1 = min3f(acc[0][jj][3], acc[1][jj][0], acc[1][jj][1]);
            float t2 = min3f(acc[1][jj][2], acc[1][jj][3], acc[2][jj][0]);
            float t3 = min3f(acc[2][jj][1], acc[2][jj][2], acc[2][jj][3]);
            float t4 = min3f(acc[3][jj][0], acc[3][jj][1], acc[3][jj][2]);
            float t  = fminf(min3f(t0, t1, t2), min3f(t3, t4, acc[3][jj][3]));
            atomicMin(&colmin[mtl][wc * 64 + (s & 1) * 32 + jj * 16 + c], __float_as_int(t));
        }
    };

    bhalf8 bf0[2][3], bf1[2][3];
    loadB(0, bf0);
    #pragma unroll 1
    for (int s = 0; s < 16; s += 2) {
        loadB(s + 1, bf1);
        process(s, bf0);
        if (s + 2 < 16) loadB(s + 2, bf0);
        process(s + 1, bf1);
    }

    // ---- flush: LDS row combine, then global atomicMin partials ----
    #pragma unroll
    for (int i = 0; i < 4; i++)
        #pragma unroll
        for (int r = 0; r < 4; r++)
            atomicMin(&rowmin[wr * 64 + i * 16 + q * 4 + r], __float_as_int(rv[i][r]));
    __syncthreads();

    if (tid < 128)
        atomicMin(&rowglob[(size_t)(b * 64 + nt) * 128 + tid], rowmin[tid]);
    #pragma unroll
    for (int k = 0; k < 4; k++) {
        const int idx = k * 256 + tid;       // 0..1023 = mtl*128 + col
        const int mtl = idx >> 7, col = idx & 127;
        atomicMin(&colglob[(size_t)(b * 64 + mc * 8 + mtl) * 128 + col], colmin[mtl][col]);
    }
    __syncthreads();   // all this block's flush atomics issued & drained (barrier waits vmcnt)

    // ---- distributed finalize: gates[0..255]=(b,nt) rows (8 contrib), [256..511]=(b,mt) cols (64) ----
    __shared__ int flags[9];
    __shared__ float wsum[2];
    if (tid < 9) {
        __threadfence();   // release our flush atomics
        int old;
        if (tid == 0) old = atomicAdd(&gates[b * 64 + nt], 1) - 6;          // ==1 iff old==7
        else          old = atomicAdd(&gates[256 + b * 64 + mc * 8 + tid - 1], 1) - 62;
        flags[tid] = (old == 1);
    }
    __syncthreads();
    #pragma unroll 1
    for (int g = 0; g < 9; g++) {
        if (flags[g]) {                       // block-uniform branch
            __threadfence();                  // acquire all contributors' atomics
            const int* src = (g == 0) ? &rowglob[(size_t)(b * 64 + nt) * 128]
                                      : &colglob[(size_t)(b * 64 + mc * 8 + g - 1) * 128];
            float v = 0.f;
            if (tid < 128)
                v = __int_as_float(__hip_atomic_load(&src[tid], __ATOMIC_RELAXED,
                                                     __HIP_MEMORY_SCOPE_AGENT));
            #pragma unroll
            for (int m = 1; m < 64; m <<= 1) v += __shfl_xor(v, m, 64);
            if (lane == 0 && tid < 128) wsum[wave] = v;
            __syncthreads();
            if (tid == 0)
                atomicAdd(out, (wsum[0] + wsum[1]) * (1.0f / ((float)B_ * (float)N_)));
            __syncthreads();
        }
    }
}

extern "C" void kernel_launch(void* const* d_in, const int* in_sizes, int n_in,
                              void* d_out, int out_size, void* d_ws, size_t ws_size,
                              hipStream_t stream) {
    const float* f  = (const float*)d_in[0];
    const float* f2 = (const float*)d_in[1];
    char* ws = (char*)d_ws;
    unsigned short* Ap = (unsigned short*)(ws + OFF_A);
    unsigned short* Bp = (unsigned short*)(ws + OFF_B);
    int* rowglob = (int*)(ws + OFF_RG);
    int* colglob = (int*)(ws + OFF_CG);
    int* gates   = (int*)(ws + OFF_GT);
    float* out   = (float*)d_out;

    // prep: fragment layout + norm fusion; inits rowglob/colglob/gates/out
    chamfer_prep<<<dim3(1024), dim3(256), 0, stream>>>(f, f2, Ap, Bp, rowglob, out);

    // main: 2048 blocks; last contributor per point-group folds its sum into out
    chamfer_tile<<<dim3(8, NT_, B_), dim3(256), 0, stream>>>(Ap, Bp, rowglob, colglob, gates, out);
}

// Round 13
// 139.829 us; speedup vs baseline: 2.3006x; 2.3006x over previous
//
#include <hip/hip_runtime.h>
#include <hip/hip_bf16.h>
#include <stdint.h>

// Problem constants (fixed by reference)
#define B_  4
#define N_  8192
#define M_  8192
#define D_  64
#define KP  96    // padded K: 64 data + (norm_hi, norm_lo, 1, 1) + 28 zeros
#define NT_ 64
#define MT_ 64
#define RBN ((B_ * N_) / 16)     // 2048 16-row blocks on A side
#define INF_BITS 0x7F800000      // +inf bits; signed-int min == float min for our range

typedef __attribute__((ext_vector_type(8))) short bhalf8;   // 8 bf16 (MFMA A/B frag)
typedef __attribute__((ext_vector_type(4))) float f32x4;    // MFMA C/D frag

// ---- workspace layout ----
// A'/B': bf16 fragment-chunk order (see prep). K=96 fuses norms so MFMA emits full distances.
// rowglob[32768] colglob[32768]: per-point mins (float bits, atomicMin-accumulated).
// LESSONS: (R8) never clamp regs via launch_bounds min-waves -> spill; (R9) keep LDS small;
// (R10/R11) NO __threadfence / in-kernel cross-block finalize on multi-XCD: agent fences
// writeback/invalidate per-XCD L2 and destroy operand locality -> 2-5x loop slowdown.
// Fence-free 3-dispatch structure (R7) is the proven correct+fast scheme.
static const size_t OFF_A   = 0;
static const size_t OFF_B   = (size_t)B_ * N_ * KP * 2;                   // 6,291,456
static const size_t OFF_RG  = OFF_B + (size_t)B_ * M_ * KP * 2;           // 12,582,912
static const size_t OFF_CG  = OFF_RG + (size_t)B_ * N_ * 4;               // +128 KB

__device__ __forceinline__ short bf16bits(float x) {
    union { __hip_bfloat16 h; unsigned short u; } cv;
    cv.h = __float2bfloat16(x);
    return (short)cv.u;
}
__device__ __forceinline__ float min3f(float a, float b, float c) {
    return fminf(fminf(a, b), c);   // -> v_min3_f32
}

// ---------------- prep: K=96 fused-norm fragment layout; init min buffers + out ----------------
__global__ __launch_bounds__(256) void chamfer_prep(
        const float* __restrict__ f, const float* __restrict__ f2,
        unsigned short* __restrict__ Ap, unsigned short* __restrict__ Bp,
        int* __restrict__ minbuf, float* __restrict__ out) {
    const int tid = threadIdx.x;
    const int gid = blockIdx.x * 256 + tid;
    if (gid == 0) out[0] = 0.f;
    if (gid < 65536) minbuf[gid] = INF_BITS;         // rowglob + colglob

    const int w = gid >> 6;                          // 16-row block id, 0..4095
    const int lane = tid & 63;
    const int q = lane >> 4, c = lane & 15;
    const bool isA = w < RBN;
    const int rb = isA ? w : w - RBN;
    const float* src = isA ? f : f2;
    unsigned short* dst = isA ? Ap : Bp;
    const float scale = isA ? -2.0f : 1.0f;          // fold the -2 into A; exact in bf16

    const float* row = src + ((size_t)rb * 16 + c) * 64;
    f32x4 u0 = *(const f32x4*)(row + q * 8);
    f32x4 u1 = *(const f32x4*)(row + q * 8 + 4);
    f32x4 u2 = *(const f32x4*)(row + 32 + q * 8);
    f32x4 u3 = *(const f32x4*)(row + 32 + q * 8 + 4);

    float ss = 0.f;
    #pragma unroll
    for (int k = 0; k < 4; k++)
        ss += u0[k] * u0[k] + u1[k] * u1[k] + u2[k] * u2[k] + u3[k] * u3[k];
    ss += __shfl_xor(ss, 16, 64);
    ss += __shfl_xor(ss, 32, 64);                    // full ||row c||^2 in every lane

    bhalf8 o0, o1;
    #pragma unroll
    for (int k = 0; k < 4; k++) {
        o0[k]     = bf16bits(u0[k] * scale);
        o0[4 + k] = bf16bits(u1[k] * scale);
        o1[k]     = bf16bits(u2[k] * scale);
        o1[4 + k] = bf16bits(u3[k] * scale);
    }
    bhalf8 o2 = {0, 0, 0, 0, 0, 0, 0, 0};            // k=64..95 zeros except q==0 lanes
    if (q == 0) {
        float nh = __bfloat162float(__float2bfloat16(ss));  // hi part, exact in bf16
        float nl = ss - nh;                                  // residual
        const short one = 0x3F80;                            // bf16 1.0
        if (isA) { o2[0] = bf16bits(nh); o2[1] = bf16bits(nl); o2[2] = one; o2[3] = one; }
        else     { o2[0] = one; o2[1] = one; o2[2] = bf16bits(nh); o2[3] = bf16bits(nl); }
    }
    *(bhalf8*)(dst + ((size_t)(rb * 3 + 0) * 64 + lane) * 8) = o0;
    *(bhalf8*)(dst + ((size_t)(rb * 3 + 1) * 64 + lane) * 8) = o1;
    *(bhalf8*)(dst + ((size_t)(rb * 3 + 2) * 64 + lane) * 8) = o2;
}

// ---------------- tile kernel: mtl-granular double-buffered prefetch (distance ~232 cyc) ----------------
// grid (mc=8, nt=64, b=4); x=mc so (linear%8)==mc -> per-XCD B-stripe affinity (perf heuristic).
// Per wave-iter (one mtl = 128 cols): 12 frag loads prefetched one FULL iteration ahead
// (48 MFMA ~= 232 pipe cyc >= ~200 cyc L2 latency -> exposed latency ~0), 48 MFMA,
// 32 row-min v_min3, 2x col min3-tree + fire-and-forget ds_min. No barriers in the loop.
__global__ __launch_bounds__(256) void chamfer_tile(
        const unsigned short* __restrict__ Ap, const unsigned short* __restrict__ Bp,
        int* __restrict__ rowglob, int* __restrict__ colglob) {
    const int mc = blockIdx.x;   // 0..7 : 8-tile mt chunk
    const int nt = blockIdx.y;   // 0..63
    const int b  = blockIdx.z;   // 0..3
    const int tid = threadIdx.x;
    const int wave = tid >> 6, lane = tid & 63;
    const int wr = wave >> 1, wc = wave & 1;
    const int q = lane >> 4, c = lane & 15;

    __shared__ int colmin[8][128];   // per-mt col mins, float bits, signed-int order (4 KB)
    __shared__ int rowmin[128];
    #pragma unroll
    for (int k = 0; k < 4; k++) ((int*)colmin)[k * 256 + tid] = INF_BITS;
    if (tid < 128) rowmin[tid] = INF_BITS;
    __syncthreads();

    // A fragments: rows nt*128 + wr*64 + i*16 + c, 3 k-steps. Loaded once (48 VGPR).
    const int rbA0 = b * 512 + nt * 8 + wr * 4;
    bhalf8 af[4][3];
    #pragma unroll
    for (int i = 0; i < 4; i++)
        #pragma unroll
        for (int ks = 0; ks < 3; ks++)
            af[i][ks] = *(const bhalf8*)(Ap + ((size_t)((rbA0 + i) * 3 + ks) * 64 + lane) * 8);

    f32x4 rv[4];                 // running row-min, rows i*16+q*4+r (this wave's 64 rows)
    #pragma unroll
    for (int i = 0; i < 4; i++) rv[i] = (f32x4){3.0e38f, 3.0e38f, 3.0e38f, 3.0e38f};

    const f32x4 zero4 = {0.f, 0.f, 0.f, 0.f};

    // B pointer for mtl: rb = b*512 + (mc*8+mtl)*8 + wc*4 + rbo, rbo=half*2+jj in 0..3.
    // Shorts: rb*1536 + ks*512 + lane*8. Per-mtl advance: 8 rb = 12288 shorts.
    const unsigned short* pB = Bp + (size_t)(b * 512 + mc * 64 + wc * 4) * 1536 + lane * 8;

    bhalf8 bufs[2][4][3];        // [buf][rbo][ks] : 96 VGPR
    auto loadMtl = [&](const unsigned short* p, bhalf8 (&bf)[4][3]) {
        #pragma unroll
        for (int r = 0; r < 4; r++)
            #pragma unroll
            for (int ks = 0; ks < 3; ks++)
                bf[r][ks] = *(const bhalf8*)(p + r * 1536 + ks * 512);
    };

    auto processHalf = [&](int mtl, int half, bhalf8 (&bf)[4][3]) {
        f32x4 acc[4][2];
        #pragma unroll
        for (int i = 0; i < 4; i++)
            #pragma unroll
            for (int jj = 0; jj < 2; jj++)
                acc[i][jj] = __builtin_amdgcn_mfma_f32_16x16x32_bf16(
                                 af[i][0], bf[half * 2 + jj][0], zero4, 0, 0, 0);
        #pragma unroll
        for (int ks = 1; ks < 3; ks++)
            #pragma unroll
            for (int i = 0; i < 4; i++)
                #pragma unroll
                for (int jj = 0; jj < 2; jj++)
                    acc[i][jj] = __builtin_amdgcn_mfma_f32_16x16x32_bf16(
                                     af[i][ks], bf[half * 2 + jj][ks], acc[i][jj], 0, 0, 0);
        // acc[i][jj][r] = d(row nt*128+wr*64+i*16+q*4+r, col (mc*8+mtl)*128+wc*64+half*32+jj*16+c)

        // row-min: 16 v_min3
        #pragma unroll
        for (int i = 0; i < 4; i++)
            #pragma unroll
            for (int r = 0; r < 4; r++)
                rv[i][r] = fminf(fminf(acc[i][0][r], acc[i][1][r]), rv[i][r]);

        // col-min over this lane's 16 rows: balanced min3 tree -> fire-and-forget ds_min
        #pragma unroll
        for (int jj = 0; jj < 2; jj++) {
            float t0 = min3f(acc[0][jj][0], acc[0][jj][1], acc[0][jj][2]);
            float t1 = min3f(acc[0][jj][3], acc[1][jj][0], acc[1][jj][1]);
            float t2 = min3f(acc[1][jj][2], acc[1][jj][3], acc[2][jj][0]);
            float t3 = min3f(acc[2][jj][1], acc[2][jj][2], acc[2][jj][3]);
            float t4 = min3f(acc[3][jj][0], acc[3][jj][1], acc[3][jj][2]);
            float t  = fminf(min3f(t0, t1, t2), min3f(t3, t4, acc[3][jj][3]));
            atomicMin(&colmin[mtl][wc * 64 + half * 32 + jj * 16 + c], __float_as_int(t));
        }
    };

    loadMtl(pB, bufs[0]);
    loadMtl(pB + 12288, bufs[1]);
    pB += 24576;
    #pragma unroll 2
    for (int mtl = 0; mtl < 8; mtl++) {
        processHalf(mtl, 0, bufs[mtl & 1]);
        processHalf(mtl, 1, bufs[mtl & 1]);
        if (mtl < 6) { loadMtl(pB, bufs[mtl & 1]); pB += 12288; }  // prefetch mtl+2
    }

    // ---- flush: LDS row combine, then global atomicMin partials (fence-free; R7-proven) ----
    #pragma unroll
    for (int i = 0; i < 4; i++)
        #pragma unroll
        for (int r = 0; r < 4; r++)
            atomicMin(&rowmin[wr * 64 + i * 16 + q * 4 + r], __float_as_int(rv[i][r]));
    __syncthreads();

    if (tid < 128)
        atomicMin(&rowglob[(size_t)(b * 64 + nt) * 128 + tid], rowmin[tid]);
    #pragma unroll
    for (int k = 0; k < 4; k++) {
        const int idx = k * 256 + tid;       // 0..1023 = mtl*128 + col
        const int mtl = idx >> 7, col = idx & 127;
        atomicMin(&colglob[(size_t)(b * 64 + mc * 8 + mtl) * 128 + col], colmin[mtl][col]);
    }
}

// ---------------- finalize: mean of rowglob + colglob (256 KB total) ----------------
__global__ __launch_bounds__(256) void chamfer_finalize(
        const int* __restrict__ rowglob, const int* __restrict__ colglob,
        float* __restrict__ out) {
    const int gid = blockIdx.x * 256 + threadIdx.x;   // 64 blocks -> 16384 threads
    float s = 0.f;
    #pragma unroll
    for (int k = 0; k < 2; k++) {
        s += __int_as_float(rowglob[gid + k * 16384]) * (1.0f / ((float)B_ * (float)N_));
        s += __int_as_float(colglob[gid + k * 16384]) * (1.0f / ((float)B_ * (float)M_));
    }
    __shared__ float sb[256];
    const int tid = threadIdx.x;
    sb[tid] = s;
    __syncthreads();
    for (int st = 128; st > 0; st >>= 1) {
        if (tid < st) sb[tid] += sb[tid + st];
        __syncthreads();
    }
    if (tid == 0) atomicAdd(out, sb[0]);
}

extern "C" void kernel_launch(void* const* d_in, const int* in_sizes, int n_in,
                              void* d_out, int out_size, void* d_ws, size_t ws_size,
                              hipStream_t stream) {
    const float* f  = (const float*)d_in[0];
    const float* f2 = (const float*)d_in[1];
    char* ws = (char*)d_ws;
    unsigned short* Ap = (unsigned short*)(ws + OFF_A);
    unsigned short* Bp = (unsigned short*)(ws + OFF_B);
    int* rowglob = (int*)(ws + OFF_RG);
    int* colglob = (int*)(ws + OFF_CG);
    float* out   = (float*)d_out;

    // prep: fragment layout + norm fusion; inits rowglob/colglob/out
    chamfer_prep<<<dim3(1024), dim3(256), 0, stream>>>(f, f2, Ap, Bp, rowglob, out);

    // main: 2048 blocks, deep-prefetch loop
    chamfer_tile<<<dim3(8, NT_, B_), dim3(256), 0, stream>>>(Ap, Bp, rowglob, colglob);

    // finalize: 256 KB read + block sums -> scalar
    chamfer_finalize<<<dim3(64), dim3(256), 0, stream>>>(rowglob, colglob, out);
}